// Round 9
// baseline (785.823 us; speedup 1.0000x reference)
//
#include <hip/hip_runtime.h>
#include <hip/hip_fp16.h>
#include <math.h>

#define EMB 32
#define NFEAT 128
#define RANGE 256               // nodes per bucket (dst >> 8)
#define NBUCK_MAX 512           // supports n <= 131072
#define FILL_TILE 4096          // edges per k_bfill block (16 per thread)
#define FIN_CAP 12288           // max (padded) edges per bucket staged in LDS (48 KB)
#define PAD_SLACK (RANGE * 14)  // per-bucket pad: both halves -> mult 8 (<=7 each)

__device__ __forceinline__ float lrelu(float z) { return z > 0.f ? z : 0.01f * z; }

// ---------------------------------------------------------------------------
// Embed: x = lrelu(nf @ W_embed + b_embed); m = lrelu(x @ W_msg + b_msg) [fp16]
// 8 lanes/node, lane c owns channels 4c..4c+3. Row in NAMED float4 regs
// (r0..r3) with fully static unrolls -> no scratch (rule #20 fix).
// Per k: one wave-broadcast ds_read_b128 of W + shfl + 4 fma.
// ---------------------------------------------------------------------------
__global__ __launch_bounds__(256) void k_embed(
    const float* __restrict__ nf, const float* __restrict__ Wemb,
    const float* __restrict__ bemb, const float* __restrict__ Wmsg,
    const float* __restrict__ bmsg, float* __restrict__ x,
    __half* __restrict__ m, int n)
{
    __shared__ float sW[NFEAT * EMB];   // 16 KB
    __shared__ float sWm[EMB * EMB];    // 4 KB
    int t = threadIdx.x;
    for (int i = t; i < NFEAT * EMB; i += 256) sW[i] = Wemb[i];
    for (int i = t; i < EMB * EMB; i += 256) sWm[i] = Wmsg[i];
    __syncthreads();

    int c = t & 7;          // channel quad
    int g = t >> 3;         // node slot: 0..31 per block
    int node = blockIdx.x * 32 + g;     // exact grid: one node per slot
    if (node >= n) return;

    float4 be = ((const float4*)bemb)[c];
    float4 bm = ((const float4*)bmsg)[c];

    const float4* rp = (const float4*)(nf + (size_t)node * NFEAT + c * 16);
    float4 r0 = rp[0], r1 = rp[1], r2 = rp[2], r3 = rp[3];

    float4 acc = be;
#define EMB_STEP(RQ, COMP, K) {                                   \
        float xa = __shfl(RQ.COMP, s, 8);                         \
        float4 wv = *(const float4*)&sW[(K) * EMB + 4 * c];       \
        acc.x = fmaf(xa, wv.x, acc.x);                            \
        acc.y = fmaf(xa, wv.y, acc.y);                            \
        acc.z = fmaf(xa, wv.z, acc.z);                            \
        acc.w = fmaf(xa, wv.w, acc.w); }
    #pragma unroll
    for (int s = 0; s < 8; ++s) {
        EMB_STEP(r0, x, s * 16 + 0)  EMB_STEP(r0, y, s * 16 + 1)
        EMB_STEP(r0, z, s * 16 + 2)  EMB_STEP(r0, w, s * 16 + 3)
        EMB_STEP(r1, x, s * 16 + 4)  EMB_STEP(r1, y, s * 16 + 5)
        EMB_STEP(r1, z, s * 16 + 6)  EMB_STEP(r1, w, s * 16 + 7)
        EMB_STEP(r2, x, s * 16 + 8)  EMB_STEP(r2, y, s * 16 + 9)
        EMB_STEP(r2, z, s * 16 + 10) EMB_STEP(r2, w, s * 16 + 11)
        EMB_STEP(r3, x, s * 16 + 12) EMB_STEP(r3, y, s * 16 + 13)
        EMB_STEP(r3, z, s * 16 + 14) EMB_STEP(r3, w, s * 16 + 15)
    }
#undef EMB_STEP

    float x0 = lrelu(acc.x), x1 = lrelu(acc.y);
    float x2 = lrelu(acc.z), x3 = lrelu(acc.w);
    float4 xs; xs.x = x0; xs.y = x1; xs.z = x2; xs.w = x3;
    ((float4*)x)[(unsigned)node * 8u + (unsigned)c] = xs;

    float4 ma = bm;
#define MSG_STEP(XV, K) {                                         \
        float xa = __shfl(XV, s, 8);                              \
        float4 wv = *(const float4*)&sWm[(K) * EMB + 4 * c];      \
        ma.x = fmaf(xa, wv.x, ma.x);                              \
        ma.y = fmaf(xa, wv.y, ma.y);                              \
        ma.z = fmaf(xa, wv.z, ma.z);                              \
        ma.w = fmaf(xa, wv.w, ma.w); }
    #pragma unroll
    for (int s = 0; s < 8; ++s) {
        MSG_STEP(x0, s * 4 + 0) MSG_STEP(x1, s * 4 + 1)
        MSG_STEP(x2, s * 4 + 2) MSG_STEP(x3, s * 4 + 3)
    }
#undef MSG_STEP

    float2 m0; m0.x = lrelu(ma.x); m0.y = lrelu(ma.y);
    float2 m1; m1.x = lrelu(ma.z); m1.y = lrelu(ma.w);
    __half2 h0 = __float22half2_rn(m0);
    __half2 h1 = __float22half2_rn(m1);
    uint2 st;
    st.x = *(unsigned*)&h0;
    st.y = *(unsigned*)&h1;
    *(uint2*)(m + (unsigned)node * 32u + 4u * (unsigned)c) = st;
}

// ---------------------------------------------------------------------------
// Bucketed CSR build. Bucket b = dst>>8; edges packed as (src<<8)|(dst&255).
// ---------------------------------------------------------------------------
__global__ __launch_bounds__(256) void k_bhist(
    const int* __restrict__ dst, int* __restrict__ bucket_cnt, int E, int nbuck)
{
    __shared__ int h[NBUCK_MAX];
    int t = threadIdx.x;
    for (int i = t; i < nbuck; i += 256) h[i] = 0;
    __syncthreads();
    for (int i = blockIdx.x * 256 + t; i < E; i += gridDim.x * 256)
        atomicAdd(&h[dst[i] >> 8], 1);
    __syncthreads();
    for (int i = t; i < nbuck; i += 256)
        if (h[i]) atomicAdd(&bucket_cnt[i], h[i]);
}

__global__ __launch_bounds__(512) void k_bscan(
    const int* __restrict__ bucket_cnt, int* __restrict__ bucket_base,
    int* __restrict__ bucket_cur, int nbuck)
{
    __shared__ int s[NBUCK_MAX];
    int t = threadIdx.x;
    int c = (t < nbuck) ? ((bucket_cnt[t] + PAD_SLACK + 16 + 15) & ~15) : 0;
    s[t] = c;
    __syncthreads();
    for (int off = 1; off < NBUCK_MAX; off <<= 1) {
        int add = (t >= off) ? s[t - off] : 0;
        __syncthreads();
        s[t] += add;
        __syncthreads();
    }
    if (t < nbuck) {
        int base = s[t] - c;
        bucket_base[t] = base;
        bucket_cur[t] = base;
    }
}

__global__ __launch_bounds__(256) void k_bfill(
    const int* __restrict__ src, const int* __restrict__ dst,
    int* __restrict__ bucket_cur, unsigned int* __restrict__ csrp, int E)
{
    __shared__ int scnt[NBUCK_MAX];
    __shared__ int gbase[NBUCK_MAX];
    int t = threadIdx.x;
    for (int i = t; i < NBUCK_MAX; i += 256) scnt[i] = 0;
    __syncthreads();

    unsigned int vals[16];
    int br[16];
    int base = blockIdx.x * FILL_TILE;
    #pragma unroll
    for (int k = 0; k < 16; ++k) {
        int e = base + k * 256 + t;
        if (e < E) {
            int d = dst[e];
            int s = src[e];
            int b = d >> 8;
            int r = atomicAdd(&scnt[b], 1);          // LDS atomic: tile-local rank
            vals[k] = ((unsigned int)s << 8) | (unsigned int)(d & 255);
            br[k] = (b << 13) | r;                    // r < 4096 fits 13 bits
        } else br[k] = -1;
    }
    __syncthreads();
    for (int i = t; i < NBUCK_MAX; i += 256) {
        int c = scnt[i];
        gbase[i] = c ? atomicAdd(&bucket_cur[i], c) : 0;
    }
    __syncthreads();
    #pragma unroll
    for (int k = 0; k < 16; ++k) {
        if (br[k] >= 0) {
            int b = br[k] >> 13;
            int r = br[k] & 8191;
            csrp[gbase[b] + r] = vals[k];
        }
    }
}

// One block per bucket: counting-sort by (dst_local, src>=half) in LDS.
// Both sub-runs padded to mult 8, pads = zero-row index n.
// rowpd[node] = (run start, p0|(p1<<16)). Sorted src list written IN PLACE.
__global__ __launch_bounds__(256) void k_csrfin(
    unsigned int* __restrict__ csrp, const int* __restrict__ bucket_base,
    const int* __restrict__ bucket_cnt, int2* __restrict__ rowpd,
    int n, int half)
{
    __shared__ int lh[2 * RANGE];
    __shared__ int pst[2 * RANGE];
    __shared__ int lc[2 * RANGE];
    __shared__ int psum[RANGE];
    __shared__ int ssrc[FIN_CAP];
    int bk = blockIdx.x;
    int t = threadIdx.x;
    int base = bucket_base[bk];
    int cnt = bucket_cnt[bk];
    if (cnt > FIN_CAP - PAD_SLACK) cnt = FIN_CAP - PAD_SLACK;

    lh[t] = 0;
    lh[t + RANGE] = 0;
    __syncthreads();
    for (int i = t; i < cnt; i += 256) {
        unsigned int v = csrp[base + i];
        int dl = (int)(v & 255u);
        int s = (int)(v >> 8);
        atomicAdd(&lh[dl * 2 + (s >= half ? 1 : 0)], 1);
    }
    __syncthreads();
    int c0 = lh[2 * t];
    int c1 = lh[2 * t + 1];
    int p0 = (c0 + 7) & ~7;
    int p1 = (c1 + 7) & ~7;
    psum[t] = p0 + p1;
    __syncthreads();
    for (int off = 1; off < RANGE; off <<= 1) {
        int add = (t >= off) ? psum[t - off] : 0;
        __syncthreads();
        psum[t] += add;
        __syncthreads();
    }
    int excl = psum[t] - (p0 + p1);
    pst[2 * t] = excl;
    pst[2 * t + 1] = excl + p0;
    lc[2 * t] = excl;
    lc[2 * t + 1] = excl + p0;
    int node = bk * RANGE + t;
    if (node < n) {
        int2 rp; rp.x = base + excl; rp.y = p0 | (p1 << 16);
        rowpd[node] = rp;
    }
    __syncthreads();
    for (int i = t; i < cnt; i += 256) {
        unsigned int v = csrp[base + i];
        int dl = (int)(v & 255u);
        int s = (int)(v >> 8);
        int key = dl * 2 + (s >= half ? 1 : 0);
        int p = atomicAdd(&lc[key], 1);
        ssrc[p] = s;
    }
    __syncthreads();
    for (int i = c0; i < p0; ++i) ssrc[pst[2 * t] + i] = n;
    for (int i = c1; i < p1; ++i) ssrc[pst[2 * t + 1] + i] = n;
    __syncthreads();
    int ptot = psum[RANGE - 1];
    for (int i = t; i < ptot; i += 256)
        csrp[base + i] = (unsigned int)ssrc[i];
}

// ---------------------------------------------------------------------------
// Gather: 8 lanes/node, lane c owns channels 4c..4c+3 (half4 = 8B load).
// Exact grid: one node per slot (no grid-stride imbalance).
// PHASE 0: half-0 sub-run (low 3.2 MB of m, L2-resident), acc = 0.
// PHASE 1: half-1 sub-run, acc initialized from agg (RMW).
// ---------------------------------------------------------------------------
__device__ __forceinline__ void gacc(const __half* __restrict__ mp,
                                     unsigned idx, unsigned c4, float4& acc)
{
    uint2 r = *(const uint2*)(mp + idx * 32u + c4);
    __half2 h0 = *(__half2*)&r.x;
    __half2 h1 = *(__half2*)&r.y;
    float2 f0 = __half22float2(h0);
    float2 f1 = __half22float2(h1);
    acc.x += f0.x; acc.y += f0.y; acc.z += f1.x; acc.w += f1.y;
}

template<int PHASE>
__global__ __launch_bounds__(256) void k_gather(
    const __half* __restrict__ m_in, float* __restrict__ agg,
    const int2* __restrict__ rowpd, const unsigned int* __restrict__ csrp, int n)
{
    int t = threadIdx.x;
    unsigned c4 = (unsigned)((t & 7) * 4);
    int g = t >> 3;
    int node = blockIdx.x * 32 + g;
    if (node >= n) return;

    int2 rp = rowpd[node];
    int p0 = rp.y & 0xffff;
    const uint4* ip;
    int nch;
    float4 acc;
    if (PHASE == 0) {
        ip = (const uint4*)(csrp + rp.x);
        nch = p0 >> 3;
        acc.x = 0.f; acc.y = 0.f; acc.z = 0.f; acc.w = 0.f;
    } else {
        ip = (const uint4*)(csrp + rp.x + p0);
        nch = rp.y >> 19;
        acc = ((const float4*)agg)[(unsigned)node * 8u + (unsigned)(t & 7)];
    }
    for (int cc = 0; cc < nch; ++cc) {
        uint4 ia = ip[2 * cc];
        uint4 ib = ip[2 * cc + 1];
        gacc(m_in, ia.x, c4, acc);
        gacc(m_in, ia.y, c4, acc);
        gacc(m_in, ia.z, c4, acc);
        gacc(m_in, ia.w, c4, acc);
        gacc(m_in, ib.x, c4, acc);
        gacc(m_in, ib.y, c4, acc);
        gacc(m_in, ib.z, c4, acc);
        gacc(m_in, ib.w, c4, acc);
    }
    ((float4*)agg)[(unsigned)node * 8u + (unsigned)(t & 7)] = acc;
}

// ---------------------------------------------------------------------------
// 16-lane-per-node GEMM helper (lane cp holds channels 2cp, 2cp+1).
// ---------------------------------------------------------------------------
__device__ __forceinline__ float2 gemm16(float2 v, const float* __restrict__ W, int cp)
{
    float2 u; u.x = 0.f; u.y = 0.f;
    #pragma unroll
    for (int kk = 0; kk < 16; ++kk) {
        float xa = __shfl(v.x, kk, 16);       // channel 2kk
        float xb = __shfl(v.y, kk, 16);       // channel 2kk+1
        float2 w0 = *(const float2*)&W[(2 * kk) * EMB + 2 * cp];
        float2 w1 = *(const float2*)&W[(2 * kk + 1) * EMB + 2 * cp];
        u.x = fmaf(xa, w0.x, u.x); u.y = fmaf(xa, w0.y, u.y);
        u.x = fmaf(xb, w1.x, u.x); u.y = fmaf(xb, w1.y, u.y);
    }
    return u;
}

// ---------------------------------------------------------------------------
// Update pass (streaming): x = lrelu([x, agg] @ W_upd + b_upd);
// optional next message (fp16) and column-sum. Exact grid: 16 nodes/block.
// ---------------------------------------------------------------------------
template<int DO_MSG, int DO_COLSUM>
__global__ __launch_bounds__(256) void k_upd(
    float* __restrict__ x, const float* __restrict__ agg,
    __half* __restrict__ m_out,
    const float* __restrict__ Wupd, const float* __restrict__ bupd,
    const float* __restrict__ Wmsg, const float* __restrict__ bmsg,
    float* __restrict__ sums, int n)
{
    __shared__ float sW[2 * EMB * EMB];   // 8 KB
    __shared__ float sWm[EMB * EMB];      // 4 KB
    __shared__ float2 red[16][16];        // 2 KB
    int t = threadIdx.x;
    for (int i = t; i < 2 * EMB * EMB; i += 256) sW[i] = Wupd[i];
    if (DO_MSG)
        for (int i = t; i < EMB * EMB; i += 256) sWm[i] = Wmsg[i];
    __syncthreads();

    int cp = t & 15;
    int g = t >> 4;
    int node = blockIdx.x * 16 + g;
    float2 colacc; colacc.x = 0.f; colacc.y = 0.f;
    if (node < n) {
        float2 bu = ((const float2*)bupd)[cp];
        float2 x2 = ((const float2*)x)[(unsigned)node * 16u + cp];
        float2 a2 = ((const float2*)agg)[(unsigned)node * 16u + cp];
        float2 u = gemm16(x2, sW, cp);
        float2 v = gemm16(a2, sW + EMB * EMB, cp);
        float2 xn;
        xn.x = lrelu(u.x + v.x + bu.x);
        xn.y = lrelu(u.y + v.y + bu.y);
        ((float2*)x)[(unsigned)node * 16u + cp] = xn;
        if (DO_MSG) {
            float2 bm2 = ((const float2*)bmsg)[cp];
            float2 mm = gemm16(xn, sWm, cp);
            mm.x = lrelu(mm.x + bm2.x);
            mm.y = lrelu(mm.y + bm2.y);
            *(__half2*)(m_out + (unsigned)node * 32u + 2u * cp) = __float22half2_rn(mm);
        }
        if (DO_COLSUM) { colacc.x += xn.x; colacc.y += xn.y; }
    }
    if (DO_COLSUM) {
        red[g][cp] = colacc;
        __syncthreads();
        if (t < 16) {
            float2 s2; s2.x = 0.f; s2.y = 0.f;
            #pragma unroll
            for (int gg = 0; gg < 16; ++gg) {
                s2.x += red[gg][t].x;
                s2.y += red[gg][t].y;
            }
            atomicAdd(&sums[2 * t], s2.x);
            atomicAdd(&sums[2 * t + 1], s2.y);
        }
    }
}

// ---------------------------------------------------------------------------
// Head: value = mean(x) @ W_val + b_val; probs = softmax(x[act] @ W_pol + b_pol)
// ---------------------------------------------------------------------------
__global__ __launch_bounds__(1024) void k_head(
    const float* __restrict__ x, const int* __restrict__ act,
    const float* __restrict__ Wval, const float* __restrict__ bval,
    const float* __restrict__ Wpol, const float* __restrict__ bpol,
    const float* __restrict__ sums, float* __restrict__ out, int n, int A)
{
    __shared__ float sred[64];
    int t = threadIdx.x;
    int w = t >> 6;
    int lane = t & 63;
    int nwaves = (blockDim.x + 63) >> 6;

    float logit = -INFINITY;
    if (t < A) {
        int node = act[t];
        float acc = bpol[0];
        #pragma unroll
        for (int k = 0; k < EMB; ++k)
            acc = fmaf(x[(size_t)node * EMB + k], Wpol[k], acc);
        logit = acc;
    }
    float wm = logit;
    for (int off = 32; off; off >>= 1) wm = fmaxf(wm, __shfl_xor(wm, off, 64));
    if (lane == 0) sred[w] = wm;
    __syncthreads();
    if (t == 0) {
        float mm = -INFINITY;
        for (int i = 0; i < nwaves; ++i) mm = fmaxf(mm, sred[i]);
        sred[32] = mm;
    }
    __syncthreads();
    float bmax = sred[32];
    float ex = (t < A) ? __expf(logit - bmax) : 0.f;
    float ws = ex;
    for (int off = 32; off; off >>= 1) ws += __shfl_xor(ws, off, 64);
    if (lane == 0) sred[w] = ws;
    __syncthreads();
    if (t == 0) {
        float ss = 0.f;
        for (int i = 0; i < nwaves; ++i) ss += sred[i];
        sred[33] = ss;
        float val = bval[0];
        float inv_n = 1.f / (float)n;
        #pragma unroll
        for (int k = 0; k < EMB; ++k) val = fmaf(sums[k] * inv_n, Wval[k], val);
        out[0] = val;
    }
    __syncthreads();
    float tot = sred[33];
    if (t < A) out[1 + t] = ex / tot;
}

// ---------------------------------------------------------------------------
extern "C" void kernel_launch(void* const* d_in, const int* in_sizes, int n_in,
                              void* d_out, int out_size, void* d_ws, size_t ws_size,
                              hipStream_t stream)
{
    const float* nf   = (const float*)d_in[0];
    const int*   ei   = (const int*)d_in[1];
    const int*   act  = (const int*)d_in[2];
    const float* Wemb = (const float*)d_in[3];
    const float* bemb = (const float*)d_in[4];
    const float* Wmsg = (const float*)d_in[5];
    const float* bmsg = (const float*)d_in[6];
    const float* Wupd = (const float*)d_in[7];
    const float* bupd = (const float*)d_in[8];
    const float* Wval = (const float*)d_in[9];
    const float* bval = (const float*)d_in[10];
    const float* Wpol = (const float*)d_in[11];
    const float* bpol = (const float*)d_in[12];

    int n = in_sizes[0] / NFEAT;
    int E = in_sizes[1] / 2;
    int A = in_sizes[2];
    const int* src = ei;
    const int* dst = ei + E;
    int nbuck = (n + RANGE - 1) / RANGE;          // 391 for n=100000
    int half = n / 2;

    char* w = (char*)d_ws;
    auto alloc = [&](size_t bytes) -> void* {
        void* p = (void*)w;
        w += (bytes + 255) & ~(size_t)255;
        return p;
    };
    float*  x    = (float*)alloc((size_t)n * EMB * 4);
    float*  agg  = (float*)alloc((size_t)n * EMB * 4);
    __half* mA   = (__half*)alloc((size_t)(n + 1) * EMB * 2);  // row n = zero row
    __half* mB   = (__half*)alloc((size_t)(n + 1) * EMB * 2);
    int2*   rowpd = (int2*)alloc((size_t)n * 8);
    int*    bucket_cnt  = (int*)alloc((size_t)nbuck * 4);
    int*    bucket_base = (int*)alloc((size_t)nbuck * 4);
    int*    bucket_cur  = (int*)alloc((size_t)nbuck * 4);
    unsigned int* csrp  = (unsigned int*)alloc(((size_t)E + (size_t)nbuck * (PAD_SLACK + 32)) * 4);
    float*  sums = (float*)alloc(EMB * 4);

    hipMemsetAsync(bucket_cnt, 0, (size_t)nbuck * 4, stream);
    hipMemsetAsync(sums, 0, EMB * 4, stream);
    hipMemsetAsync(mA + (size_t)n * EMB, 0, EMB * 2, stream);  // zero row
    hipMemsetAsync(mB + (size_t)n * EMB, 0, EMB * 2, stream);

    int nb32 = (n + 31) / 32;     // exact grids: one node per slot
    int nb16 = (n + 15) / 16;

    // embed (+ first message pass)
    k_embed<<<nb32, 256, 0, stream>>>(nf, Wemb, bemb, Wmsg, bmsg, x, mA, n);

    // CSR build: counting sort by dst, sub-runs split by src-half
    k_bhist<<<256, 256, 0, stream>>>(dst, bucket_cnt, E, nbuck);
    k_bscan<<<1, NBUCK_MAX, 0, stream>>>(bucket_cnt, bucket_base, bucket_cur, nbuck);
    int nfill = (E + FILL_TILE - 1) / FILL_TILE;
    k_bfill<<<nfill, 256, 0, stream>>>(src, dst, bucket_cur, csrp, E);
    k_csrfin<<<nbuck, 256, 0, stream>>>(csrp, bucket_base, bucket_cnt, rowpd, n, half);

    // 5 MP iterations: gather low half, RMW high half, then streaming update
    __half* mi = mA;
    __half* mo = mB;
    for (int it = 0; it < 5; ++it) {
        k_gather<0><<<nb32, 256, 0, stream>>>(mi, agg, rowpd, csrp, n);
        k_gather<1><<<nb32, 256, 0, stream>>>(mi, agg, rowpd, csrp, n);
        if (it < 4)
            k_upd<1, 0><<<nb16, 256, 0, stream>>>(x, agg, mo, Wupd, bupd, Wmsg, bmsg, sums, n);
        else
            k_upd<0, 1><<<nb16, 256, 0, stream>>>(x, agg, mo, Wupd, bupd, Wmsg, bmsg, sums, n);
        __half* tmp = mi; mi = mo; mo = tmp;
    }

    k_head<<<1, 1024, 0, stream>>>(x, act, Wval, bval, Wpol, bpol, sums,
                                   (float*)d_out, n, A);
}

// Round 10
// 738.932 us; speedup vs baseline: 1.0635x; 1.0635x over previous
//
#include <hip/hip_runtime.h>
#include <hip/hip_fp16.h>
#include <math.h>

#define EMB 32
#define NFEAT 128
#define RANGE 256               // nodes per bucket (dst >> 8)
#define NBUCK_MAX 512           // supports n <= 131072
#define FILL_TILE 4096          // edges per k_bfill block (16 per thread)
#define FIN_CAP 12288           // max (padded) edges per bucket staged in LDS (48 KB)
#define PAD_SLACK (RANGE * 14)  // per-bucket pad: both halves -> mult 8 (<=7 each)

__device__ __forceinline__ float lrelu(float z) { return z > 0.f ? z : 0.01f * z; }

// ---------------------------------------------------------------------------
// Embed: x = lrelu(nf @ W_embed + b_embed); m = lrelu(x @ W_msg + b_msg) [fp16]
// 8 lanes/node, lane c owns channels 4c..4c+3. Row in NAMED float4 regs.
// GRID-STRIDE (balanced: ~2 nodes/slot) so the 20 KB weight staging is
// amortized -- exact-grid staging was the R9 regression.
// ---------------------------------------------------------------------------
__global__ __launch_bounds__(256) void k_embed(
    const float* __restrict__ nf, const float* __restrict__ Wemb,
    const float* __restrict__ bemb, const float* __restrict__ Wmsg,
    const float* __restrict__ bmsg, float* __restrict__ x,
    __half* __restrict__ m, int n)
{
    __shared__ float sW[NFEAT * EMB];   // 16 KB
    __shared__ float sWm[EMB * EMB];    // 4 KB
    int t = threadIdx.x;
    for (int i = t; i < NFEAT * EMB / 4; i += 256)
        ((float4*)sW)[i] = ((const float4*)Wemb)[i];
    for (int i = t; i < EMB * EMB / 4; i += 256)
        ((float4*)sWm)[i] = ((const float4*)Wmsg)[i];
    __syncthreads();

    int c = t & 7;          // channel quad
    int g = t >> 3;         // node slot: 0..31 per block
    float4 be = ((const float4*)bemb)[c];
    float4 bm = ((const float4*)bmsg)[c];

    for (int node = blockIdx.x * 32 + g; node < n; node += gridDim.x * 32) {
        const float4* rp = (const float4*)(nf + (size_t)node * NFEAT + c * 16);
        float4 r0 = rp[0], r1 = rp[1], r2 = rp[2], r3 = rp[3];

        float4 acc = be;
#define EMB_STEP(RQ, COMP, K) {                                   \
        float xa = __shfl(RQ.COMP, s, 8);                         \
        float4 wv = *(const float4*)&sW[(K) * EMB + 4 * c];       \
        acc.x = fmaf(xa, wv.x, acc.x);                            \
        acc.y = fmaf(xa, wv.y, acc.y);                            \
        acc.z = fmaf(xa, wv.z, acc.z);                            \
        acc.w = fmaf(xa, wv.w, acc.w); }
        #pragma unroll
        for (int s = 0; s < 8; ++s) {
            EMB_STEP(r0, x, s * 16 + 0)  EMB_STEP(r0, y, s * 16 + 1)
            EMB_STEP(r0, z, s * 16 + 2)  EMB_STEP(r0, w, s * 16 + 3)
            EMB_STEP(r1, x, s * 16 + 4)  EMB_STEP(r1, y, s * 16 + 5)
            EMB_STEP(r1, z, s * 16 + 6)  EMB_STEP(r1, w, s * 16 + 7)
            EMB_STEP(r2, x, s * 16 + 8)  EMB_STEP(r2, y, s * 16 + 9)
            EMB_STEP(r2, z, s * 16 + 10) EMB_STEP(r2, w, s * 16 + 11)
            EMB_STEP(r3, x, s * 16 + 12) EMB_STEP(r3, y, s * 16 + 13)
            EMB_STEP(r3, z, s * 16 + 14) EMB_STEP(r3, w, s * 16 + 15)
        }
#undef EMB_STEP

        float x0 = lrelu(acc.x), x1 = lrelu(acc.y);
        float x2 = lrelu(acc.z), x3 = lrelu(acc.w);
        float4 xs; xs.x = x0; xs.y = x1; xs.z = x2; xs.w = x3;
        ((float4*)x)[(unsigned)node * 8u + (unsigned)c] = xs;

        float4 ma = bm;
#define MSG_STEP(XV, K) {                                         \
        float xa = __shfl(XV, s, 8);                              \
        float4 wv = *(const float4*)&sWm[(K) * EMB + 4 * c];      \
        ma.x = fmaf(xa, wv.x, ma.x);                              \
        ma.y = fmaf(xa, wv.y, ma.y);                              \
        ma.z = fmaf(xa, wv.z, ma.z);                              \
        ma.w = fmaf(xa, wv.w, ma.w); }
        #pragma unroll
        for (int s = 0; s < 8; ++s) {
            MSG_STEP(x0, s * 4 + 0) MSG_STEP(x1, s * 4 + 1)
            MSG_STEP(x2, s * 4 + 2) MSG_STEP(x3, s * 4 + 3)
        }
#undef MSG_STEP

        float2 m0; m0.x = lrelu(ma.x); m0.y = lrelu(ma.y);
        float2 m1; m1.x = lrelu(ma.z); m1.y = lrelu(ma.w);
        __half2 h0 = __float22half2_rn(m0);
        __half2 h1 = __float22half2_rn(m1);
        uint2 st;
        st.x = *(unsigned*)&h0;
        st.y = *(unsigned*)&h1;
        *(uint2*)(m + (unsigned)node * 32u + 4u * (unsigned)c) = st;
    }
}

// ---------------------------------------------------------------------------
// Bucketed CSR build. Bucket b = dst>>8; edges packed as (src<<8)|(dst&255).
// ---------------------------------------------------------------------------
__global__ __launch_bounds__(256) void k_bhist(
    const int* __restrict__ dst, int* __restrict__ bucket_cnt, int E, int nbuck)
{
    __shared__ int h[NBUCK_MAX];
    int t = threadIdx.x;
    for (int i = t; i < nbuck; i += 256) h[i] = 0;
    __syncthreads();
    for (int i = blockIdx.x * 256 + t; i < E; i += gridDim.x * 256)
        atomicAdd(&h[dst[i] >> 8], 1);
    __syncthreads();
    for (int i = t; i < nbuck; i += 256)
        if (h[i]) atomicAdd(&bucket_cnt[i], h[i]);
}

__global__ __launch_bounds__(512) void k_bscan(
    const int* __restrict__ bucket_cnt, int* __restrict__ bucket_base,
    int* __restrict__ bucket_cur, int nbuck)
{
    __shared__ int s[NBUCK_MAX];
    int t = threadIdx.x;
    int c = (t < nbuck) ? ((bucket_cnt[t] + PAD_SLACK + 16 + 15) & ~15) : 0;
    s[t] = c;
    __syncthreads();
    for (int off = 1; off < NBUCK_MAX; off <<= 1) {
        int add = (t >= off) ? s[t - off] : 0;
        __syncthreads();
        s[t] += add;
        __syncthreads();
    }
    if (t < nbuck) {
        int base = s[t] - c;
        bucket_base[t] = base;
        bucket_cur[t] = base;
    }
}

__global__ __launch_bounds__(256) void k_bfill(
    const int* __restrict__ src, const int* __restrict__ dst,
    int* __restrict__ bucket_cur, unsigned int* __restrict__ csrp, int E)
{
    __shared__ int scnt[NBUCK_MAX];
    __shared__ int gbase[NBUCK_MAX];
    int t = threadIdx.x;
    for (int i = t; i < NBUCK_MAX; i += 256) scnt[i] = 0;
    __syncthreads();

    unsigned int vals[16];
    int br[16];
    int base = blockIdx.x * FILL_TILE;
    #pragma unroll
    for (int k = 0; k < 16; ++k) {
        int e = base + k * 256 + t;
        if (e < E) {
            int d = dst[e];
            int s = src[e];
            int b = d >> 8;
            int r = atomicAdd(&scnt[b], 1);          // LDS atomic: tile-local rank
            vals[k] = ((unsigned int)s << 8) | (unsigned int)(d & 255);
            br[k] = (b << 13) | r;                    // r < 4096 fits 13 bits
        } else br[k] = -1;
    }
    __syncthreads();
    for (int i = t; i < NBUCK_MAX; i += 256) {
        int c = scnt[i];
        gbase[i] = c ? atomicAdd(&bucket_cur[i], c) : 0;
    }
    __syncthreads();
    #pragma unroll
    for (int k = 0; k < 16; ++k) {
        if (br[k] >= 0) {
            int b = br[k] >> 13;
            int r = br[k] & 8191;
            csrp[gbase[b] + r] = vals[k];
        }
    }
}

// One block per bucket: counting-sort by (dst_local, src>=half) in LDS.
// Both sub-runs padded to mult 8, pads = zero-row index n.
// rowpd[node] = (run start, p0|(p1<<16)). Sorted src list written IN PLACE.
__global__ __launch_bounds__(256) void k_csrfin(
    unsigned int* __restrict__ csrp, const int* __restrict__ bucket_base,
    const int* __restrict__ bucket_cnt, int2* __restrict__ rowpd,
    int n, int half)
{
    __shared__ int lh[2 * RANGE];
    __shared__ int pst[2 * RANGE];
    __shared__ int lc[2 * RANGE];
    __shared__ int psum[RANGE];
    __shared__ int ssrc[FIN_CAP];
    int bk = blockIdx.x;
    int t = threadIdx.x;
    int base = bucket_base[bk];
    int cnt = bucket_cnt[bk];
    if (cnt > FIN_CAP - PAD_SLACK) cnt = FIN_CAP - PAD_SLACK;

    lh[t] = 0;
    lh[t + RANGE] = 0;
    __syncthreads();
    for (int i = t; i < cnt; i += 256) {
        unsigned int v = csrp[base + i];
        int dl = (int)(v & 255u);
        int s = (int)(v >> 8);
        atomicAdd(&lh[dl * 2 + (s >= half ? 1 : 0)], 1);
    }
    __syncthreads();
    int c0 = lh[2 * t];
    int c1 = lh[2 * t + 1];
    int p0 = (c0 + 7) & ~7;
    int p1 = (c1 + 7) & ~7;
    psum[t] = p0 + p1;
    __syncthreads();
    for (int off = 1; off < RANGE; off <<= 1) {
        int add = (t >= off) ? psum[t - off] : 0;
        __syncthreads();
        psum[t] += add;
        __syncthreads();
    }
    int excl = psum[t] - (p0 + p1);
    pst[2 * t] = excl;
    pst[2 * t + 1] = excl + p0;
    lc[2 * t] = excl;
    lc[2 * t + 1] = excl + p0;
    int node = bk * RANGE + t;
    if (node < n) {
        int2 rp; rp.x = base + excl; rp.y = p0 | (p1 << 16);
        rowpd[node] = rp;
    }
    __syncthreads();
    for (int i = t; i < cnt; i += 256) {
        unsigned int v = csrp[base + i];
        int dl = (int)(v & 255u);
        int s = (int)(v >> 8);
        int key = dl * 2 + (s >= half ? 1 : 0);
        int p = atomicAdd(&lc[key], 1);
        ssrc[p] = s;
    }
    __syncthreads();
    for (int i = c0; i < p0; ++i) ssrc[pst[2 * t] + i] = n;
    for (int i = c1; i < p1; ++i) ssrc[pst[2 * t + 1] + i] = n;
    __syncthreads();
    int ptot = psum[RANGE - 1];
    for (int i = t; i < ptot; i += 256)
        csrp[base + i] = (unsigned int)ssrc[i];
}

// ---------------------------------------------------------------------------
// Gather: 8 lanes/node, lane c owns channels 4c..4c+3 (half4 = 8B load).
// No LDS staging -> exact grid is fine here.
// PHASE 0: half-0 sub-run (low 3.2 MB of m, L2-resident), acc = 0.
// PHASE 1: half-1 sub-run, acc initialized from agg (RMW).
// ---------------------------------------------------------------------------
__device__ __forceinline__ void gacc(const __half* __restrict__ mp,
                                     unsigned idx, unsigned c4, float4& acc)
{
    uint2 r = *(const uint2*)(mp + idx * 32u + c4);
    __half2 h0 = *(__half2*)&r.x;
    __half2 h1 = *(__half2*)&r.y;
    float2 f0 = __half22float2(h0);
    float2 f1 = __half22float2(h1);
    acc.x += f0.x; acc.y += f0.y; acc.z += f1.x; acc.w += f1.y;
}

template<int PHASE>
__global__ __launch_bounds__(256) void k_gather(
    const __half* __restrict__ m_in, float* __restrict__ agg,
    const int2* __restrict__ rowpd, const unsigned int* __restrict__ csrp, int n)
{
    int t = threadIdx.x;
    unsigned c4 = (unsigned)((t & 7) * 4);
    int g = t >> 3;
    int node = blockIdx.x * 32 + g;
    if (node >= n) return;

    int2 rp = rowpd[node];
    int p0 = rp.y & 0xffff;
    const uint4* ip;
    int nch;
    float4 acc;
    if (PHASE == 0) {
        ip = (const uint4*)(csrp + rp.x);
        nch = p0 >> 3;
        acc.x = 0.f; acc.y = 0.f; acc.z = 0.f; acc.w = 0.f;
    } else {
        ip = (const uint4*)(csrp + rp.x + p0);
        nch = rp.y >> 19;
        acc = ((const float4*)agg)[(unsigned)node * 8u + (unsigned)(t & 7)];
    }
    for (int cc = 0; cc < nch; ++cc) {
        uint4 ia = ip[2 * cc];
        uint4 ib = ip[2 * cc + 1];
        gacc(m_in, ia.x, c4, acc);
        gacc(m_in, ia.y, c4, acc);
        gacc(m_in, ia.z, c4, acc);
        gacc(m_in, ia.w, c4, acc);
        gacc(m_in, ib.x, c4, acc);
        gacc(m_in, ib.y, c4, acc);
        gacc(m_in, ib.z, c4, acc);
        gacc(m_in, ib.w, c4, acc);
    }
    ((float4*)agg)[(unsigned)node * 8u + (unsigned)(t & 7)] = acc;
}

// ---------------------------------------------------------------------------
// 16-lane-per-node GEMM helper (lane cp holds channels 2cp, 2cp+1).
// ---------------------------------------------------------------------------
__device__ __forceinline__ float2 gemm16(float2 v, const float* __restrict__ W, int cp)
{
    float2 u; u.x = 0.f; u.y = 0.f;
    #pragma unroll
    for (int kk = 0; kk < 16; ++kk) {
        float xa = __shfl(v.x, kk, 16);       // channel 2kk
        float xb = __shfl(v.y, kk, 16);       // channel 2kk+1
        float2 w0 = *(const float2*)&W[(2 * kk) * EMB + 2 * cp];
        float2 w1 = *(const float2*)&W[(2 * kk + 1) * EMB + 2 * cp];
        u.x = fmaf(xa, w0.x, u.x); u.y = fmaf(xa, w0.y, u.y);
        u.x = fmaf(xb, w1.x, u.x); u.y = fmaf(xb, w1.y, u.y);
    }
    return u;
}

// ---------------------------------------------------------------------------
// Update pass (streaming): x = lrelu([x, agg] @ W_upd + b_upd);
// optional next message (fp16) and column-sum.
// GRID-STRIDE (balanced: 4 nodes/slot) to amortize the weight staging.
// ---------------------------------------------------------------------------
template<int DO_MSG, int DO_COLSUM>
__global__ __launch_bounds__(256) void k_upd(
    float* __restrict__ x, const float* __restrict__ agg,
    __half* __restrict__ m_out,
    const float* __restrict__ Wupd, const float* __restrict__ bupd,
    const float* __restrict__ Wmsg, const float* __restrict__ bmsg,
    float* __restrict__ sums, int n)
{
    __shared__ float sW[2 * EMB * EMB];   // 8 KB
    __shared__ float sWm[EMB * EMB];      // 4 KB
    __shared__ float2 red[16][16];        // 2 KB
    int t = threadIdx.x;
    for (int i = t; i < 2 * EMB * EMB / 4; i += 256)
        ((float4*)sW)[i] = ((const float4*)Wupd)[i];
    if (DO_MSG)
        for (int i = t; i < EMB * EMB / 4; i += 256)
            ((float4*)sWm)[i] = ((const float4*)Wmsg)[i];
    __syncthreads();

    int cp = t & 15;
    int g = t >> 4;
    float2 bu = ((const float2*)bupd)[cp];
    float2 bm2;
    if (DO_MSG) bm2 = ((const float2*)bmsg)[cp];
    float2 colacc; colacc.x = 0.f; colacc.y = 0.f;
    for (int node = blockIdx.x * 16 + g; node < n; node += gridDim.x * 16) {
        float2 x2 = ((const float2*)x)[(unsigned)node * 16u + cp];
        float2 a2 = ((const float2*)agg)[(unsigned)node * 16u + cp];
        float2 u = gemm16(x2, sW, cp);
        float2 v = gemm16(a2, sW + EMB * EMB, cp);
        float2 xn;
        xn.x = lrelu(u.x + v.x + bu.x);
        xn.y = lrelu(u.y + v.y + bu.y);
        ((float2*)x)[(unsigned)node * 16u + cp] = xn;
        if (DO_MSG) {
            float2 mm = gemm16(xn, sWm, cp);
            mm.x = lrelu(mm.x + bm2.x);
            mm.y = lrelu(mm.y + bm2.y);
            *(__half2*)(m_out + (unsigned)node * 32u + 2u * cp) = __float22half2_rn(mm);
        }
        if (DO_COLSUM) { colacc.x += xn.x; colacc.y += xn.y; }
    }
    if (DO_COLSUM) {
        red[g][cp] = colacc;
        __syncthreads();
        if (t < 16) {
            float2 s2; s2.x = 0.f; s2.y = 0.f;
            #pragma unroll
            for (int gg = 0; gg < 16; ++gg) {
                s2.x += red[gg][t].x;
                s2.y += red[gg][t].y;
            }
            atomicAdd(&sums[2 * t], s2.x);
            atomicAdd(&sums[2 * t + 1], s2.y);
        }
    }
}

// ---------------------------------------------------------------------------
// Head: value = mean(x) @ W_val + b_val; probs = softmax(x[act] @ W_pol + b_pol)
// ---------------------------------------------------------------------------
__global__ __launch_bounds__(1024) void k_head(
    const float* __restrict__ x, const int* __restrict__ act,
    const float* __restrict__ Wval, const float* __restrict__ bval,
    const float* __restrict__ Wpol, const float* __restrict__ bpol,
    const float* __restrict__ sums, float* __restrict__ out, int n, int A)
{
    __shared__ float sred[64];
    int t = threadIdx.x;
    int w = t >> 6;
    int lane = t & 63;
    int nwaves = (blockDim.x + 63) >> 6;

    float logit = -INFINITY;
    if (t < A) {
        int node = act[t];
        float acc = bpol[0];
        #pragma unroll
        for (int k = 0; k < EMB; ++k)
            acc = fmaf(x[(size_t)node * EMB + k], Wpol[k], acc);
        logit = acc;
    }
    float wm = logit;
    for (int off = 32; off; off >>= 1) wm = fmaxf(wm, __shfl_xor(wm, off, 64));
    if (lane == 0) sred[w] = wm;
    __syncthreads();
    if (t == 0) {
        float mm = -INFINITY;
        for (int i = 0; i < nwaves; ++i) mm = fmaxf(mm, sred[i]);
        sred[32] = mm;
    }
    __syncthreads();
    float bmax = sred[32];
    float ex = (t < A) ? __expf(logit - bmax) : 0.f;
    float ws = ex;
    for (int off = 32; off; off >>= 1) ws += __shfl_xor(ws, off, 64);
    if (lane == 0) sred[w] = ws;
    __syncthreads();
    if (t == 0) {
        float ss = 0.f;
        for (int i = 0; i < nwaves; ++i) ss += sred[i];
        sred[33] = ss;
        float val = bval[0];
        float inv_n = 1.f / (float)n;
        #pragma unroll
        for (int k = 0; k < EMB; ++k) val = fmaf(sums[k] * inv_n, Wval[k], val);
        out[0] = val;
    }
    __syncthreads();
    float tot = sred[33];
    if (t < A) out[1 + t] = ex / tot;
}

// ---------------------------------------------------------------------------
extern "C" void kernel_launch(void* const* d_in, const int* in_sizes, int n_in,
                              void* d_out, int out_size, void* d_ws, size_t ws_size,
                              hipStream_t stream)
{
    const float* nf   = (const float*)d_in[0];
    const int*   ei   = (const int*)d_in[1];
    const int*   act  = (const int*)d_in[2];
    const float* Wemb = (const float*)d_in[3];
    const float* bemb = (const float*)d_in[4];
    const float* Wmsg = (const float*)d_in[5];
    const float* bmsg = (const float*)d_in[6];
    const float* Wupd = (const float*)d_in[7];
    const float* bupd = (const float*)d_in[8];
    const float* Wval = (const float*)d_in[9];
    const float* bval = (const float*)d_in[10];
    const float* Wpol = (const float*)d_in[11];
    const float* bpol = (const float*)d_in[12];

    int n = in_sizes[0] / NFEAT;
    int E = in_sizes[1] / 2;
    int A = in_sizes[2];
    const int* src = ei;
    const int* dst = ei + E;
    int nbuck = (n + RANGE - 1) / RANGE;          // 391 for n=100000
    int half = n / 2;

    char* w = (char*)d_ws;
    auto alloc = [&](size_t bytes) -> void* {
        void* p = (void*)w;
        w += (bytes + 255) & ~(size_t)255;
        return p;
    };
    float*  x    = (float*)alloc((size_t)n * EMB * 4);
    float*  agg  = (float*)alloc((size_t)n * EMB * 4);
    __half* mA   = (__half*)alloc((size_t)(n + 1) * EMB * 2);  // row n = zero row
    __half* mB   = (__half*)alloc((size_t)(n + 1) * EMB * 2);
    int2*   rowpd = (int2*)alloc((size_t)n * 8);
    int*    bucket_cnt  = (int*)alloc((size_t)nbuck * 4);
    int*    bucket_base = (int*)alloc((size_t)nbuck * 4);
    int*    bucket_cur  = (int*)alloc((size_t)nbuck * 4);
    unsigned int* csrp  = (unsigned int*)alloc(((size_t)E + (size_t)nbuck * (PAD_SLACK + 32)) * 4);
    float*  sums = (float*)alloc(EMB * 4);

    hipMemsetAsync(bucket_cnt, 0, (size_t)nbuck * 4, stream);
    hipMemsetAsync(sums, 0, EMB * 4, stream);
    hipMemsetAsync(mA + (size_t)n * EMB, 0, EMB * 2, stream);  // zero row
    hipMemsetAsync(mB + (size_t)n * EMB, 0, EMB * 2, stream);

    int nb32 = (n + 31) / 32;        // exact grid for staging-free gathers
    // balanced grid-stride grids for weight-staging kernels:
    // 1563 blocks * 32 slots * 2 passes = 100032 >= n (embed, exactly 2/slot)
    // 1563 blocks * 16 slots * 4 passes = 100032 >= n (upd, exactly 4/slot)
    int nb_amort = 1563;

    // embed (+ first message pass)
    k_embed<<<nb_amort, 256, 0, stream>>>(nf, Wemb, bemb, Wmsg, bmsg, x, mA, n);

    // CSR build: counting sort by dst, sub-runs split by src-half
    k_bhist<<<256, 256, 0, stream>>>(dst, bucket_cnt, E, nbuck);
    k_bscan<<<1, NBUCK_MAX, 0, stream>>>(bucket_cnt, bucket_base, bucket_cur, nbuck);
    int nfill = (E + FILL_TILE - 1) / FILL_TILE;
    k_bfill<<<nfill, 256, 0, stream>>>(src, dst, bucket_cur, csrp, E);
    k_csrfin<<<nbuck, 256, 0, stream>>>(csrp, bucket_base, bucket_cnt, rowpd, n, half);

    // 5 MP iterations: gather low half, RMW high half, then streaming update
    __half* mi = mA;
    __half* mo = mB;
    for (int it = 0; it < 5; ++it) {
        k_gather<0><<<nb32, 256, 0, stream>>>(mi, agg, rowpd, csrp, n);
        k_gather<1><<<nb32, 256, 0, stream>>>(mi, agg, rowpd, csrp, n);
        if (it < 4)
            k_upd<1, 0><<<nb_amort, 256, 0, stream>>>(x, agg, mo, Wupd, bupd, Wmsg, bmsg, sums, n);
        else
            k_upd<0, 1><<<nb_amort, 256, 0, stream>>>(x, agg, mo, Wupd, bupd, Wmsg, bmsg, sums, n);
        __half* tmp = mi; mi = mo; mo = tmp;
    }

    k_head<<<1, 1024, 0, stream>>>(x, act, Wval, bval, Wpol, bpol, sums,
                                   (float*)d_out, n, A);
}

// Round 11
// 648.183 us; speedup vs baseline: 1.2123x; 1.1400x over previous
//
#include <hip/hip_runtime.h>
#include <hip/hip_fp16.h>
#include <math.h>

#define EMB 32
#define NFEAT 128
#define RANGE 256               // nodes per bucket (dst >> 8)
#define NBUCK_MAX 512           // supports n <= 131072
#define FILL_TILE 4096          // edges per k_bfill block (16 per thread)
#define FIN_CAP 12288           // max (padded) edges per bucket staged in LDS (48 KB)
#define PAD_SLACK (RANGE * 14)  // per-bucket pad: both halves -> mult 8 (<=7 each)

__device__ __forceinline__ float lrelu(float z) { return z > 0.f ? z : 0.01f * z; }

// ---------------------------------------------------------------------------
// Embed: x = lrelu(nf @ W_embed + b_embed); m = lrelu(x @ W_msg + b_msg) [fp16]
// 8 lanes/node, lane c owns channels 4c..4c+3. Row in NAMED float4 regs.
// OUTER LOOPS ROLLED (#pragma unroll 1): bounds the scheduler's load-hoisting
// window to 16 ds_read_b128 -> no VGPR blowup/spill (R10 regression fix).
// ---------------------------------------------------------------------------
__global__ __launch_bounds__(256) void k_embed(
    const float* __restrict__ nf, const float* __restrict__ Wemb,
    const float* __restrict__ bemb, const float* __restrict__ Wmsg,
    const float* __restrict__ bmsg, float* __restrict__ x,
    __half* __restrict__ m, int n)
{
    __shared__ float sW[NFEAT * EMB];   // 16 KB
    __shared__ float sWm[EMB * EMB];    // 4 KB
    int t = threadIdx.x;
    for (int i = t; i < NFEAT * EMB / 4; i += 256)
        ((float4*)sW)[i] = ((const float4*)Wemb)[i];
    for (int i = t; i < EMB * EMB / 4; i += 256)
        ((float4*)sWm)[i] = ((const float4*)Wmsg)[i];
    __syncthreads();

    int c = t & 7;          // channel quad
    int g = t >> 3;         // node slot: 0..31 per block
    float4 be = ((const float4*)bemb)[c];
    float4 bm = ((const float4*)bmsg)[c];

    for (int node = blockIdx.x * 32 + g; node < n; node += gridDim.x * 32) {
        const float4* rp = (const float4*)(nf + (size_t)node * NFEAT + c * 16);
        float4 r0 = rp[0], r1 = rp[1], r2 = rp[2], r3 = rp[3];

        float4 acc = be;
#define EMB_STEP(RQ, COMP, K) {                                   \
        float xa = __shfl(RQ.COMP, s, 8);                         \
        float4 wv = *(const float4*)&sW[(K) * EMB + 4 * c];       \
        acc.x = fmaf(xa, wv.x, acc.x);                            \
        acc.y = fmaf(xa, wv.y, acc.y);                            \
        acc.z = fmaf(xa, wv.z, acc.z);                            \
        acc.w = fmaf(xa, wv.w, acc.w); }
        #pragma unroll 1
        for (int s = 0; s < 8; ++s) {
            EMB_STEP(r0, x, s * 16 + 0)  EMB_STEP(r0, y, s * 16 + 1)
            EMB_STEP(r0, z, s * 16 + 2)  EMB_STEP(r0, w, s * 16 + 3)
            EMB_STEP(r1, x, s * 16 + 4)  EMB_STEP(r1, y, s * 16 + 5)
            EMB_STEP(r1, z, s * 16 + 6)  EMB_STEP(r1, w, s * 16 + 7)
            EMB_STEP(r2, x, s * 16 + 8)  EMB_STEP(r2, y, s * 16 + 9)
            EMB_STEP(r2, z, s * 16 + 10) EMB_STEP(r2, w, s * 16 + 11)
            EMB_STEP(r3, x, s * 16 + 12) EMB_STEP(r3, y, s * 16 + 13)
            EMB_STEP(r3, z, s * 16 + 14) EMB_STEP(r3, w, s * 16 + 15)
        }
#undef EMB_STEP

        float x0 = lrelu(acc.x), x1 = lrelu(acc.y);
        float x2 = lrelu(acc.z), x3 = lrelu(acc.w);
        float4 xs; xs.x = x0; xs.y = x1; xs.z = x2; xs.w = x3;
        ((float4*)x)[(unsigned)node * 8u + (unsigned)c] = xs;

        float4 ma = bm;
#define MSG_STEP(XV, K) {                                         \
        float xa = __shfl(XV, s, 8);                              \
        float4 wv = *(const float4*)&sWm[(K) * EMB + 4 * c];      \
        ma.x = fmaf(xa, wv.x, ma.x);                              \
        ma.y = fmaf(xa, wv.y, ma.y);                              \
        ma.z = fmaf(xa, wv.z, ma.z);                              \
        ma.w = fmaf(xa, wv.w, ma.w); }
        #pragma unroll 1
        for (int s = 0; s < 8; ++s) {
            MSG_STEP(x0, s * 4 + 0) MSG_STEP(x1, s * 4 + 1)
            MSG_STEP(x2, s * 4 + 2) MSG_STEP(x3, s * 4 + 3)
        }
#undef MSG_STEP

        float2 m0; m0.x = lrelu(ma.x); m0.y = lrelu(ma.y);
        float2 m1; m1.x = lrelu(ma.z); m1.y = lrelu(ma.w);
        __half2 h0 = __float22half2_rn(m0);
        __half2 h1 = __float22half2_rn(m1);
        uint2 st;
        st.x = *(unsigned*)&h0;
        st.y = *(unsigned*)&h1;
        *(uint2*)(m + (unsigned)node * 32u + 4u * (unsigned)c) = st;
    }
}

// ---------------------------------------------------------------------------
// Bucketed CSR build. Bucket b = dst>>8; edges packed as (src<<8)|(dst&255).
// ---------------------------------------------------------------------------
__global__ __launch_bounds__(256) void k_bhist(
    const int* __restrict__ dst, int* __restrict__ bucket_cnt, int E, int nbuck)
{
    __shared__ int h[NBUCK_MAX];
    int t = threadIdx.x;
    for (int i = t; i < nbuck; i += 256) h[i] = 0;
    __syncthreads();
    for (int i = blockIdx.x * 256 + t; i < E; i += gridDim.x * 256)
        atomicAdd(&h[dst[i] >> 8], 1);
    __syncthreads();
    for (int i = t; i < nbuck; i += 256)
        if (h[i]) atomicAdd(&bucket_cnt[i], h[i]);
}

__global__ __launch_bounds__(512) void k_bscan(
    const int* __restrict__ bucket_cnt, int* __restrict__ bucket_base,
    int* __restrict__ bucket_cur, int nbuck)
{
    __shared__ int s[NBUCK_MAX];
    int t = threadIdx.x;
    int c = (t < nbuck) ? ((bucket_cnt[t] + PAD_SLACK + 16 + 15) & ~15) : 0;
    s[t] = c;
    __syncthreads();
    for (int off = 1; off < NBUCK_MAX; off <<= 1) {
        int add = (t >= off) ? s[t - off] : 0;
        __syncthreads();
        s[t] += add;
        __syncthreads();
    }
    if (t < nbuck) {
        int base = s[t] - c;
        bucket_base[t] = base;
        bucket_cur[t] = base;
    }
}

__global__ __launch_bounds__(256) void k_bfill(
    const int* __restrict__ src, const int* __restrict__ dst,
    int* __restrict__ bucket_cur, unsigned int* __restrict__ csrp, int E)
{
    __shared__ int scnt[NBUCK_MAX];
    __shared__ int gbase[NBUCK_MAX];
    int t = threadIdx.x;
    for (int i = t; i < NBUCK_MAX; i += 256) scnt[i] = 0;
    __syncthreads();

    unsigned int vals[16];
    int br[16];
    int base = blockIdx.x * FILL_TILE;
    #pragma unroll
    for (int k = 0; k < 16; ++k) {
        int e = base + k * 256 + t;
        if (e < E) {
            int d = dst[e];
            int s = src[e];
            int b = d >> 8;
            int r = atomicAdd(&scnt[b], 1);          // LDS atomic: tile-local rank
            vals[k] = ((unsigned int)s << 8) | (unsigned int)(d & 255);
            br[k] = (b << 13) | r;                    // r < 4096 fits 13 bits
        } else br[k] = -1;
    }
    __syncthreads();
    for (int i = t; i < NBUCK_MAX; i += 256) {
        int c = scnt[i];
        gbase[i] = c ? atomicAdd(&bucket_cur[i], c) : 0;
    }
    __syncthreads();
    #pragma unroll
    for (int k = 0; k < 16; ++k) {
        if (br[k] >= 0) {
            int b = br[k] >> 13;
            int r = br[k] & 8191;
            csrp[gbase[b] + r] = vals[k];
        }
    }
}

// One block per bucket: counting-sort by (dst_local, src>=half) in LDS.
// Both sub-runs padded to mult 8, pads = zero-row index n.
// rowpd[node] = (run start, p0|(p1<<16)). Sorted src list written IN PLACE.
__global__ __launch_bounds__(256) void k_csrfin(
    unsigned int* __restrict__ csrp, const int* __restrict__ bucket_base,
    const int* __restrict__ bucket_cnt, int2* __restrict__ rowpd,
    int n, int half)
{
    __shared__ int lh[2 * RANGE];
    __shared__ int pst[2 * RANGE];
    __shared__ int lc[2 * RANGE];
    __shared__ int psum[RANGE];
    __shared__ int ssrc[FIN_CAP];
    int bk = blockIdx.x;
    int t = threadIdx.x;
    int base = bucket_base[bk];
    int cnt = bucket_cnt[bk];
    if (cnt > FIN_CAP - PAD_SLACK) cnt = FIN_CAP - PAD_SLACK;

    lh[t] = 0;
    lh[t + RANGE] = 0;
    __syncthreads();
    for (int i = t; i < cnt; i += 256) {
        unsigned int v = csrp[base + i];
        int dl = (int)(v & 255u);
        int s = (int)(v >> 8);
        atomicAdd(&lh[dl * 2 + (s >= half ? 1 : 0)], 1);
    }
    __syncthreads();
    int c0 = lh[2 * t];
    int c1 = lh[2 * t + 1];
    int p0 = (c0 + 7) & ~7;
    int p1 = (c1 + 7) & ~7;
    psum[t] = p0 + p1;
    __syncthreads();
    for (int off = 1; off < RANGE; off <<= 1) {
        int add = (t >= off) ? psum[t - off] : 0;
        __syncthreads();
        psum[t] += add;
        __syncthreads();
    }
    int excl = psum[t] - (p0 + p1);
    pst[2 * t] = excl;
    pst[2 * t + 1] = excl + p0;
    lc[2 * t] = excl;
    lc[2 * t + 1] = excl + p0;
    int node = bk * RANGE + t;
    if (node < n) {
        int2 rp; rp.x = base + excl; rp.y = p0 | (p1 << 16);
        rowpd[node] = rp;
    }
    __syncthreads();
    for (int i = t; i < cnt; i += 256) {
        unsigned int v = csrp[base + i];
        int dl = (int)(v & 255u);
        int s = (int)(v >> 8);
        int key = dl * 2 + (s >= half ? 1 : 0);
        int p = atomicAdd(&lc[key], 1);
        ssrc[p] = s;
    }
    __syncthreads();
    for (int i = c0; i < p0; ++i) ssrc[pst[2 * t] + i] = n;
    for (int i = c1; i < p1; ++i) ssrc[pst[2 * t + 1] + i] = n;
    __syncthreads();
    int ptot = psum[RANGE - 1];
    for (int i = t; i < ptot; i += 256)
        csrp[base + i] = (unsigned int)ssrc[i];
}

// ---------------------------------------------------------------------------
// Gather: 8 lanes/node, lane c owns channels 4c..4c+3 (half4 = 8B load).
// No LDS staging -> exact grid is fine here.
// PHASE 0: half-0 sub-run (low 3.2 MB of m, L2-resident), acc = 0.
// PHASE 1: half-1 sub-run, acc initialized from agg (RMW).
// ---------------------------------------------------------------------------
__device__ __forceinline__ void gacc(const __half* __restrict__ mp,
                                     unsigned idx, unsigned c4, float4& acc)
{
    uint2 r = *(const uint2*)(mp + idx * 32u + c4);
    __half2 h0 = *(__half2*)&r.x;
    __half2 h1 = *(__half2*)&r.y;
    float2 f0 = __half22float2(h0);
    float2 f1 = __half22float2(h1);
    acc.x += f0.x; acc.y += f0.y; acc.z += f1.x; acc.w += f1.y;
}

template<int PHASE>
__global__ __launch_bounds__(256) void k_gather(
    const __half* __restrict__ m_in, float* __restrict__ agg,
    const int2* __restrict__ rowpd, const unsigned int* __restrict__ csrp, int n)
{
    int t = threadIdx.x;
    unsigned c4 = (unsigned)((t & 7) * 4);
    int g = t >> 3;
    int node = blockIdx.x * 32 + g;
    if (node >= n) return;

    int2 rp = rowpd[node];
    int p0 = rp.y & 0xffff;
    const uint4* ip;
    int nch;
    float4 acc;
    if (PHASE == 0) {
        ip = (const uint4*)(csrp + rp.x);
        nch = p0 >> 3;
        acc.x = 0.f; acc.y = 0.f; acc.z = 0.f; acc.w = 0.f;
    } else {
        ip = (const uint4*)(csrp + rp.x + p0);
        nch = rp.y >> 19;
        acc = ((const float4*)agg)[(unsigned)node * 8u + (unsigned)(t & 7)];
    }
    for (int cc = 0; cc < nch; ++cc) {
        uint4 ia = ip[2 * cc];
        uint4 ib = ip[2 * cc + 1];
        gacc(m_in, ia.x, c4, acc);
        gacc(m_in, ia.y, c4, acc);
        gacc(m_in, ia.z, c4, acc);
        gacc(m_in, ia.w, c4, acc);
        gacc(m_in, ib.x, c4, acc);
        gacc(m_in, ib.y, c4, acc);
        gacc(m_in, ib.z, c4, acc);
        gacc(m_in, ib.w, c4, acc);
    }
    ((float4*)agg)[(unsigned)node * 8u + (unsigned)(t & 7)] = acc;
}

// ---------------------------------------------------------------------------
// 16-lane-per-node GEMM helper (lane cp holds channels 2cp, 2cp+1).
// ---------------------------------------------------------------------------
__device__ __forceinline__ float2 gemm16(float2 v, const float* __restrict__ W, int cp)
{
    float2 u; u.x = 0.f; u.y = 0.f;
    #pragma unroll
    for (int kk = 0; kk < 16; ++kk) {
        float xa = __shfl(v.x, kk, 16);       // channel 2kk
        float xb = __shfl(v.y, kk, 16);       // channel 2kk+1
        float2 w0 = *(const float2*)&W[(2 * kk) * EMB + 2 * cp];
        float2 w1 = *(const float2*)&W[(2 * kk + 1) * EMB + 2 * cp];
        u.x = fmaf(xa, w0.x, u.x); u.y = fmaf(xa, w0.y, u.y);
        u.x = fmaf(xb, w1.x, u.x); u.y = fmaf(xb, w1.y, u.y);
    }
    return u;
}

// ---------------------------------------------------------------------------
// Update pass (streaming): x = lrelu([x, agg] @ W_upd + b_upd);
// optional next message (fp16) and column-sum.
// GRID-STRIDE (balanced: 4 nodes/slot) to amortize the weight staging.
// ---------------------------------------------------------------------------
template<int DO_MSG, int DO_COLSUM>
__global__ __launch_bounds__(256) void k_upd(
    float* __restrict__ x, const float* __restrict__ agg,
    __half* __restrict__ m_out,
    const float* __restrict__ Wupd, const float* __restrict__ bupd,
    const float* __restrict__ Wmsg, const float* __restrict__ bmsg,
    float* __restrict__ sums, int n)
{
    __shared__ float sW[2 * EMB * EMB];   // 8 KB
    __shared__ float sWm[EMB * EMB];      // 4 KB
    __shared__ float2 red[16][16];        // 2 KB
    int t = threadIdx.x;
    for (int i = t; i < 2 * EMB * EMB / 4; i += 256)
        ((float4*)sW)[i] = ((const float4*)Wupd)[i];
    if (DO_MSG)
        for (int i = t; i < EMB * EMB / 4; i += 256)
            ((float4*)sWm)[i] = ((const float4*)Wmsg)[i];
    __syncthreads();

    int cp = t & 15;
    int g = t >> 4;
    float2 bu = ((const float2*)bupd)[cp];
    float2 bm2;
    if (DO_MSG) bm2 = ((const float2*)bmsg)[cp];
    float2 colacc; colacc.x = 0.f; colacc.y = 0.f;
    for (int node = blockIdx.x * 16 + g; node < n; node += gridDim.x * 16) {
        float2 x2 = ((const float2*)x)[(unsigned)node * 16u + cp];
        float2 a2 = ((const float2*)agg)[(unsigned)node * 16u + cp];
        float2 u = gemm16(x2, sW, cp);
        float2 v = gemm16(a2, sW + EMB * EMB, cp);
        float2 xn;
        xn.x = lrelu(u.x + v.x + bu.x);
        xn.y = lrelu(u.y + v.y + bu.y);
        ((float2*)x)[(unsigned)node * 16u + cp] = xn;
        if (DO_MSG) {
            float2 mm = gemm16(xn, sWm, cp);
            mm.x = lrelu(mm.x + bm2.x);
            mm.y = lrelu(mm.y + bm2.y);
            *(__half2*)(m_out + (unsigned)node * 32u + 2u * cp) = __float22half2_rn(mm);
        }
        if (DO_COLSUM) { colacc.x += xn.x; colacc.y += xn.y; }
    }
    if (DO_COLSUM) {
        red[g][cp] = colacc;
        __syncthreads();
        if (t < 16) {
            float2 s2; s2.x = 0.f; s2.y = 0.f;
            #pragma unroll
            for (int gg = 0; gg < 16; ++gg) {
                s2.x += red[gg][t].x;
                s2.y += red[gg][t].y;
            }
            atomicAdd(&sums[2 * t], s2.x);
            atomicAdd(&sums[2 * t + 1], s2.y);
        }
    }
}

// ---------------------------------------------------------------------------
// Head: value = mean(x) @ W_val + b_val; probs = softmax(x[act] @ W_pol + b_pol)
// ---------------------------------------------------------------------------
__global__ __launch_bounds__(1024) void k_head(
    const float* __restrict__ x, const int* __restrict__ act,
    const float* __restrict__ Wval, const float* __restrict__ bval,
    const float* __restrict__ Wpol, const float* __restrict__ bpol,
    const float* __restrict__ sums, float* __restrict__ out, int n, int A)
{
    __shared__ float sred[64];
    int t = threadIdx.x;
    int w = t >> 6;
    int lane = t & 63;
    int nwaves = (blockDim.x + 63) >> 6;

    float logit = -INFINITY;
    if (t < A) {
        int node = act[t];
        float acc = bpol[0];
        #pragma unroll
        for (int k = 0; k < EMB; ++k)
            acc = fmaf(x[(size_t)node * EMB + k], Wpol[k], acc);
        logit = acc;
    }
    float wm = logit;
    for (int off = 32; off; off >>= 1) wm = fmaxf(wm, __shfl_xor(wm, off, 64));
    if (lane == 0) sred[w] = wm;
    __syncthreads();
    if (t == 0) {
        float mm = -INFINITY;
        for (int i = 0; i < nwaves; ++i) mm = fmaxf(mm, sred[i]);
        sred[32] = mm;
    }
    __syncthreads();
    float bmax = sred[32];
    float ex = (t < A) ? __expf(logit - bmax) : 0.f;
    float ws = ex;
    for (int off = 32; off; off >>= 1) ws += __shfl_xor(ws, off, 64);
    if (lane == 0) sred[w] = ws;
    __syncthreads();
    if (t == 0) {
        float ss = 0.f;
        for (int i = 0; i < nwaves; ++i) ss += sred[i];
        sred[33] = ss;
        float val = bval[0];
        float inv_n = 1.f / (float)n;
        #pragma unroll
        for (int k = 0; k < EMB; ++k) val = fmaf(sums[k] * inv_n, Wval[k], val);
        out[0] = val;
    }
    __syncthreads();
    float tot = sred[33];
    if (t < A) out[1 + t] = ex / tot;
}

// ---------------------------------------------------------------------------
extern "C" void kernel_launch(void* const* d_in, const int* in_sizes, int n_in,
                              void* d_out, int out_size, void* d_ws, size_t ws_size,
                              hipStream_t stream)
{
    const float* nf   = (const float*)d_in[0];
    const int*   ei   = (const int*)d_in[1];
    const int*   act  = (const int*)d_in[2];
    const float* Wemb = (const float*)d_in[3];
    const float* bemb = (const float*)d_in[4];
    const float* Wmsg = (const float*)d_in[5];
    const float* bmsg = (const float*)d_in[6];
    const float* Wupd = (const float*)d_in[7];
    const float* bupd = (const float*)d_in[8];
    const float* Wval = (const float*)d_in[9];
    const float* bval = (const float*)d_in[10];
    const float* Wpol = (const float*)d_in[11];
    const float* bpol = (const float*)d_in[12];

    int n = in_sizes[0] / NFEAT;
    int E = in_sizes[1] / 2;
    int A = in_sizes[2];
    const int* src = ei;
    const int* dst = ei + E;
    int nbuck = (n + RANGE - 1) / RANGE;          // 391 for n=100000
    int half = n / 2;

    char* w = (char*)d_ws;
    auto alloc = [&](size_t bytes) -> void* {
        void* p = (void*)w;
        w += (bytes + 255) & ~(size_t)255;
        return p;
    };
    float*  x    = (float*)alloc((size_t)n * EMB * 4);
    float*  agg  = (float*)alloc((size_t)n * EMB * 4);
    __half* mA   = (__half*)alloc((size_t)(n + 1) * EMB * 2);  // row n = zero row
    __half* mB   = (__half*)alloc((size_t)(n + 1) * EMB * 2);
    int2*   rowpd = (int2*)alloc((size_t)n * 8);
    int*    bucket_cnt  = (int*)alloc((size_t)nbuck * 4);
    int*    bucket_base = (int*)alloc((size_t)nbuck * 4);
    int*    bucket_cur  = (int*)alloc((size_t)nbuck * 4);
    unsigned int* csrp  = (unsigned int*)alloc(((size_t)E + (size_t)nbuck * (PAD_SLACK + 32)) * 4);
    float*  sums = (float*)alloc(EMB * 4);

    hipMemsetAsync(bucket_cnt, 0, (size_t)nbuck * 4, stream);
    hipMemsetAsync(sums, 0, EMB * 4, stream);
    hipMemsetAsync(mA + (size_t)n * EMB, 0, EMB * 2, stream);  // zero row
    hipMemsetAsync(mB + (size_t)n * EMB, 0, EMB * 2, stream);

    int nb32 = (n + 31) / 32;        // exact grid for staging-free gathers
    int nb_amort = 1563;             // balanced grid-stride for staging kernels

    // embed (+ first message pass)
    k_embed<<<nb_amort, 256, 0, stream>>>(nf, Wemb, bemb, Wmsg, bmsg, x, mA, n);

    // CSR build: counting sort by dst, sub-runs split by src-half
    k_bhist<<<256, 256, 0, stream>>>(dst, bucket_cnt, E, nbuck);
    k_bscan<<<1, NBUCK_MAX, 0, stream>>>(bucket_cnt, bucket_base, bucket_cur, nbuck);
    int nfill = (E + FILL_TILE - 1) / FILL_TILE;
    k_bfill<<<nfill, 256, 0, stream>>>(src, dst, bucket_cur, csrp, E);
    k_csrfin<<<nbuck, 256, 0, stream>>>(csrp, bucket_base, bucket_cnt, rowpd, n, half);

    // 5 MP iterations: gather low half, RMW high half, then streaming update
    __half* mi = mA;
    __half* mo = mB;
    for (int it = 0; it < 5; ++it) {
        k_gather<0><<<nb32, 256, 0, stream>>>(mi, agg, rowpd, csrp, n);
        k_gather<1><<<nb32, 256, 0, stream>>>(mi, agg, rowpd, csrp, n);
        if (it < 4)
            k_upd<1, 0><<<nb_amort, 256, 0, stream>>>(x, agg, mo, Wupd, bupd, Wmsg, bmsg, sums, n);
        else
            k_upd<0, 1><<<nb_amort, 256, 0, stream>>>(x, agg, mo, Wupd, bupd, Wmsg, bmsg, sums, n);
        __half* tmp = mi; mi = mo; mo = tmp;
    }

    k_head<<<1, 1024, 0, stream>>>(x, act, Wval, bval, Wpol, bpol, sums,
                                   (float*)d_out, n, A);
}